// Round 5
// baseline (14.609 us; speedup 1.0000x reference)
//
#include <hip/hip_runtime.h>
#include <math.h>

#define BD 256       // 4 waves per block
#define WPB 4
#define IPW 2        // images per wave
#define NPIX 784     // 28*28
#define NOUT 10

__device__ __forceinline__ float cospix(int v) {
    // cos(pi * v / 255); v_cos_f32 input is revolutions
    return __builtin_amdgcn_cosf((float)v * (1.0f / 510.0f));
}

__global__ __launch_bounds__(BD) void quanv_analytic4_kernel(
    const int* __restrict__ x,        // (B,1,28,28) int32, 0..255
    const float* __restrict__ fc_w,   // (10,784)
    const float* __restrict__ fc_b,   // (10,)
    float* __restrict__ out,          // (B,10)
    int B)
{
    const int t    = threadIdx.x;
    const int wv   = t >> 6;
    const int lane = t & 63;
    const int b0   = (blockIdx.x * WPB + wv) * IPW;
    if (b0 >= B) return;

    const int* im0 = x + (size_t)b0 * NPIX;
    const int* im1 = im0 + NPIX;

    // ---- issue ALL cold x loads up front (16 int2 per lane, static indexing)
    int2 T0[4], C0[4], T1[4], C1[4];
#pragma unroll
    for (int k = 0; k < 4; ++k) {
        const int p = lane + 64 * k;
        if (p < 196) {
            const int i = p / 14;
            const int j = p - i * 14;
            const int base = i * 56 + j * 2;
            T0[k] = *(const int2*)(im0 + base);
            C0[k] = *(const int2*)(im0 + base + 28);
            T1[k] = *(const int2*)(im1 + base);
            C1[k] = *(const int2*)(im1 + base + 28);
        } else {
            T0[k] = make_int2(0, 0); C0[k] = make_int2(0, 0);
            T1[k] = make_int2(0, 0); C1[k] = make_int2(0, 0);
        }
    }

    float acc0[NOUT], acc1[NOUT];
#pragma unroll
    for (int o = 0; o < NOUT; ++o) { acc0[o] = 0.0f; acc1[o] = 0.0f; }

#pragma unroll
    for (int k = 0; k < 4; ++k) {
        const int p = lane + 64 * k;
        if (p < 196) {
            const float A0 = cospix(T0[k].x), B0 = cospix(T0[k].y);
            const float f20 = A0 * cospix(C0[k].x), f30 = B0 * cospix(C0[k].y);
            const float A1 = cospix(T1[k].x), B1 = cospix(T1[k].y);
            const float f21 = A1 * cospix(C1[k].x), f31 = B1 * cospix(C1[k].y);

#pragma unroll
            for (int o = 0; o < NOUT; ++o) {
                const float4 w = *(const float4*)(fc_w + o * NPIX + 4 * p);
                acc0[o] += A0 * w.x + B0 * w.y + f20 * w.z + f30 * w.w;
                acc1[o] += A1 * w.x + B1 * w.y + f21 * w.z + f31 * w.w;
            }
        }
    }

    // butterfly reduce -> every lane has the totals for both images
#pragma unroll
    for (int o = 0; o < NOUT; ++o) {
#pragma unroll
        for (int off = 32; off > 0; off >>= 1) {
            acc0[o] += __shfl_xor(acc0[o], off, 64);
            acc1[o] += __shfl_xor(acc1[o], off, 64);
        }
    }

    // lane 0 -> image b0, lane 1 -> image b0+1 (parallel softmax tails)
    if (lane < 2) {
        const int b = b0 + lane;
        float lg[NOUT];
        float m = -1e30f;
#pragma unroll
        for (int o = 0; o < NOUT; ++o) {
            const float a = (lane == 0) ? acc0[o] : acc1[o];
            lg[o] = a + fc_b[o];
            m = fmaxf(m, lg[o]);
        }
        float sum = 0.0f;
#pragma unroll
        for (int o = 0; o < NOUT; ++o) sum += expf(lg[o] - m);
        const float lse = m + logf(sum);
        float* ob = out + (size_t)b * NOUT;
#pragma unroll
        for (int o = 0; o < NOUT; ++o) ob[o] = lg[o] - lse;
    }
}

extern "C" void kernel_launch(void* const* d_in, const int* in_sizes, int n_in,
                              void* d_out, int out_size, void* d_ws, size_t ws_size,
                              hipStream_t stream) {
    const int*   x      = (const int*)d_in[0];
    // d_in[1] = params — provably cannot affect the output (unit-modulus
    // diagonal phases + basis-permutation CNOTs leave |amp|^2 invariant).
    const float* fc_w   = (const float*)d_in[2];
    const float* fc_b   = (const float*)d_in[3];
    float* out = (float*)d_out;
    const int B = in_sizes[0] / NPIX;  // 4096
    const int grid = (B + WPB * IPW - 1) / (WPB * IPW);  // 512
    quanv_analytic4_kernel<<<grid, BD, 0, stream>>>(x, fc_w, fc_b, out, B);
}